// Round 10
// baseline (440.115 us; speedup 1.0000x reference)
//
#include <hip/hip_runtime.h>
#include <hip/hip_bf16.h>
#include <math.h>

#define N_ROWS 16384
#define D_DIM  256
#define SPLIT  16
#define G      4                 // row-groups (of 16) per wave -> 64 v1 rows/wave
#define BM     256               // v1 rows per block = 4 waves * G * 16
#define TR     32                // v2 tile rows staged per iteration
#define CPB    (N_ROWS / SPLIT)  // columns swept per block = 1024
// v1 is pre-scaled by 10*log2(e): MFMA directly yields base-2 logits a'.
// sum 2^{a'} <= 16384 * 2^14.43 ~ 3.6e8 -> fits fp32, no max-subtract needed.
#define SCALE1 14.426950408889634f   // 10 * log2(e)

typedef __bf16 bf16_t;
typedef __bf16 bf16x8 __attribute__((ext_vector_type(8)));
typedef __bf16 bf16x4 __attribute__((ext_vector_type(4)));
typedef float  f32x4  __attribute__((ext_vector_type(4)));

static __device__ __forceinline__ float fast_exp2(float x) {
#if __has_builtin(__builtin_amdgcn_exp2f)
    return __builtin_amdgcn_exp2f(x);
#else
    return __expf(x * 0.6931471805599453f);
#endif
}

// ------- Kernel 1: L2-normalize both rows, cast to bf16, exact fp32 pos -----
__global__ __launch_bounds__(256) void normalize_kernel(
    const float* __restrict__ v1, const float* __restrict__ v2,
    bf16_t* __restrict__ v1n, bf16_t* __restrict__ v2n,
    float* __restrict__ pos, int n)
{
    const int row  = blockIdx.x * 4 + (threadIdx.x >> 6);
    const int lane = threadIdx.x & 63;
    if (row >= n) return;
    const float4 a = *reinterpret_cast<const float4*>(v1 + (size_t)row * D_DIM + lane * 4);
    const float4 b = *reinterpret_cast<const float4*>(v2 + (size_t)row * D_DIM + lane * 4);
    float ss1 = a.x * a.x + a.y * a.y + a.z * a.z + a.w * a.w;
    float ss2 = b.x * b.x + b.y * b.y + b.z * b.z + b.w * b.w;
    float dt  = a.x * b.x + a.y * b.y + a.z * b.z + a.w * b.w;
    #pragma unroll
    for (int off = 1; off < 64; off <<= 1) {
        ss1 += __shfl_xor(ss1, off);
        ss2 += __shfl_xor(ss2, off);
        dt  += __shfl_xor(dt,  off);
    }
    const float n1 = fmaxf(sqrtf(ss1), 1e-12f);
    const float n2 = fmaxf(sqrtf(ss2), 1e-12f);
    const float s1 = SCALE1 / n1;
    const float s2 = 1.0f   / n2;
    bf16x4 o1, o2;
    o1[0] = (bf16_t)(a.x * s1); o1[1] = (bf16_t)(a.y * s1);
    o1[2] = (bf16_t)(a.z * s1); o1[3] = (bf16_t)(a.w * s1);
    o2[0] = (bf16_t)(b.x * s2); o2[1] = (bf16_t)(b.y * s2);
    o2[2] = (bf16_t)(b.z * s2); o2[3] = (bf16_t)(b.w * s2);
    *reinterpret_cast<bf16x4*>(v1n + (size_t)row * D_DIM + lane * 4) = o1;
    *reinterpret_cast<bf16x4*>(v2n + (size_t)row * D_DIM + lane * 4) = o2;
    if (lane == 0) pos[row] = 10.0f * dt / (n1 * n2);
}

// ------- Kernel 2: base-2 logits + row sum of 2^logit ----------------------
// Swapped-operand MFMA: D = A(v2 tile) * B(v1 frag); D col (=lane&15) indexes
// the v1 row -> each lane's 4 acc values belong to ONE v1 row. G=4 row-groups
// per wave; 32-row v2 tiles double-buffered in LDS via global_load_lds
// (linear dest, XOR-pre-swizzled source; ds_read applies same XOR).
// SPLIT=16 -> 1024 blocks = 4 blocks/CU = 4 waves/SIMD: cross-wave overlap
// feeds the per-SIMD MFMA pipe (19.4 cyc/MFMA) while peers run exp/barriers.
__global__ __launch_bounds__(256, 4) void logits_kernel(
    const bf16_t* __restrict__ v1n, const bf16_t* __restrict__ v2n,
    float* __restrict__ partials)
{
    __shared__ bf16_t lds[2][TR * D_DIM];   // 2 x 16KB: [32 rows][256 bf16]

    const int tid  = threadIdx.x;
    const int w    = tid >> 6;
    const int lane = tid & 63;
    const int lo   = lane & 15;
    const int hi   = lane >> 4;
    const int xr   = lo & 7;                 // read-side XOR key
    const int r0w  = blockIdx.x * BM + w * (G * 16);

    // v1 fragments, resident for the whole sweep: [group][kk]
    bf16x8 bfrag[G][8];
    #pragma unroll
    for (int g = 0; g < G; ++g) {
        const bf16_t* v1p = v1n + (size_t)(r0w + g * 16 + lo) * D_DIM + hi * 8;
        #pragma unroll
        for (int kk = 0; kk < 8; ++kk)
            bfrag[g][kk] = *reinterpret_cast<const bf16x8*>(v1p + kk * 32);
    }

    const int cbase = blockIdx.y * CPB;
    float s[G];
    #pragma unroll
    for (int g = 0; g < G; ++g) s[g] = 0.f;

    // ---- stage tile 0 into buf 0 (source address pre-swizzled) ----
    #pragma unroll
    for (int j = 0; j < 4; ++j) {
        int r  = j * 8 + (tid >> 5);            // tile row 0..31
        int ch = (tid & 31) ^ (r & 7);          // swizzled 16B-chunk
        const bf16_t* gp = v2n + (size_t)(cbase + r) * D_DIM + ch * 8;
        __builtin_amdgcn_global_load_lds(
            (const __attribute__((address_space(1))) unsigned int*)gp,
            (__attribute__((address_space(3))) unsigned int*)(&lds[0][0] + j * 2048 + w * 512),
            16, 0, 0);
    }

    const int NT = CPB / TR;   // 32 tiles of 32 columns
    int cur = 0;
    for (int t = 0; t < NT; ++t) {
        asm volatile("s_waitcnt vmcnt(0)" ::: "memory");
        __builtin_amdgcn_s_barrier();
        asm volatile("" ::: "memory");

        // issue next tile's stage into the other buffer (in flight during MFMA)
        if (t + 1 < NT) {
            const int c0n = cbase + (t + 1) * TR;
            #pragma unroll
            for (int j = 0; j < 4; ++j) {
                int r  = j * 8 + (tid >> 5);
                int ch = (tid & 31) ^ (r & 7);
                const bf16_t* gp = v2n + (size_t)(c0n + r) * D_DIM + ch * 8;
                __builtin_amdgcn_global_load_lds(
                    (const __attribute__((address_space(1))) unsigned int*)gp,
                    (__attribute__((address_space(3))) unsigned int*)(&lds[cur ^ 1][0] + j * 2048 + w * 512),
                    16, 0, 0);
            }
        }

        const bf16_t* bufr = &lds[cur][0];
        #pragma unroll
        for (int sub = 0; sub < 2; ++sub) {      // two 16-row subtiles
            f32x4 acc[G];
            #pragma unroll
            for (int g = 0; g < G; ++g) acc[g] = (f32x4){0.f, 0.f, 0.f, 0.f};

            #pragma unroll
            for (int kk = 0; kk < 8; ++kk) {
                const int q = hi + 4 * kk;           // 16B-chunk index in row
                const bf16x8 a = *reinterpret_cast<const bf16x8*>(
                    bufr + (sub * 16 + lo) * 256 + ((q ^ xr) << 3));
                #pragma unroll
                for (int g = 0; g < G; ++g)
                    acc[g] = __builtin_amdgcn_mfma_f32_16x16x32_bf16(a, bfrag[g][kk], acc[g], 0, 0, 0);
            }

            // per logit: one v_exp_f32 + one add (no max-subtract needed)
            #pragma unroll
            for (int g = 0; g < G; ++g) {
                s[g] += (fast_exp2(acc[g][0]) + fast_exp2(acc[g][1]))
                      + (fast_exp2(acc[g][2]) + fast_exp2(acc[g][3]));
            }
        }

        asm volatile("" ::: "memory");
        __builtin_amdgcn_s_barrier();
        cur ^= 1;
    }

    // merge the 4 hi-lanes holding each row, write split partial
    #pragma unroll
    for (int g = 0; g < G; ++g) {
        float v = s[g];
        v += __shfl_xor(v, 16);
        v += __shfl_xor(v, 32);
        if (lane < 16)
            partials[(size_t)(r0w + g * 16 + lo) * SPLIT + blockIdx.y] = v;
    }
}

// ------- Kernel 3a: per-row loss + per-block partial sum -------------------
__global__ __launch_bounds__(256) void row_loss_kernel(
    const float* __restrict__ pos, const float* __restrict__ partials,
    float* __restrict__ bsum)
{
    const int row = blockIdx.x * 256 + threadIdx.x;
    float ssum = 0.f;
    #pragma unroll
    for (int p = 0; p < SPLIT; ++p)
        ssum += partials[(size_t)row * SPLIT + p];
    // ln(sum_j exp(logit_j)) == logf(sum_j 2^{a'_j})  (a' = logit*log2e)
    float loss = -pos[row] + logf(ssum);
    #pragma unroll
    for (int off = 1; off < 64; off <<= 1) loss += __shfl_xor(loss, off);
    __shared__ float ws4[4];
    if ((threadIdx.x & 63) == 0) ws4[threadIdx.x >> 6] = loss;
    __syncthreads();
    if (threadIdx.x == 0)
        bsum[blockIdx.x] = ws4[0] + ws4[1] + ws4[2] + ws4[3];
}

// ------- Kernel 3b: final mean ---------------------------------------------
__global__ void final_kernel(const float* __restrict__ bsum,
                             float* __restrict__ out, int nb, float invn)
{
    float v = (threadIdx.x < nb) ? bsum[threadIdx.x] : 0.f;
    #pragma unroll
    for (int off = 1; off < 64; off <<= 1) v += __shfl_xor(v, off);
    if (threadIdx.x == 0) out[0] = v * invn;
}

extern "C" void kernel_launch(void* const* d_in, const int* in_sizes, int n_in,
                              void* d_out, int out_size, void* d_ws, size_t ws_size,
                              hipStream_t stream)
{
    const float* view1 = (const float*)d_in[0];
    const float* view2 = (const float*)d_in[1];
    float* out = (float*)d_out;
    const int n = in_sizes[0] / D_DIM;   // 16384

    char* ws = (char*)d_ws;
    bf16_t* v1n = (bf16_t*)ws;                                    // 8 MB
    bf16_t* v2n = (bf16_t*)(ws + (size_t)n * D_DIM * 2);          // 8 MB
    char*   p2  = ws + (size_t)n * D_DIM * 4;
    float*  pos = (float*)p2;                                     // 64 KB
    float*  partials = (float*)(p2 + (size_t)n * 4);              // 1 MB
    float*  bsum = (float*)(p2 + (size_t)n * 4 + (size_t)n * SPLIT * 4); // 256 B

    // 1) normalize both views -> bf16 (+ exact fp32 pos)
    normalize_kernel<<<n / 4, 256, 0, stream>>>(view1, view2, v1n, v2n, pos, n);

    // 2) tiled base-2 logits + sumexp2 partials
    dim3 grid2(n / BM, SPLIT, 1);
    logits_kernel<<<grid2, 256, 0, stream>>>(v1n, v2n, partials);

    // 3) reduce
    row_loss_kernel<<<n / 256, 256, 0, stream>>>(pos, partials, bsum);
    final_kernel<<<1, 64, 0, stream>>>(bsum, out, n / 256, 1.0f / (float)n);
}

// Round 12
// 184.365 us; speedup vs baseline: 2.3872x; 2.3872x over previous
//
#include <hip/hip_runtime.h>
#include <hip/hip_bf16.h>
#include <math.h>

#define N_ROWS 16384
#define D_DIM  256
#define SPLIT  8
#define G      4                 // row-groups (of 16) per wave -> 64 v1 rows/wave
#define BM     256               // v1 rows per block = 4 waves * G * 16
#define TR     32                // v2 tile rows staged per iteration
#define CPB    (N_ROWS / SPLIT)  // columns swept per block = 2048
// v1 is pre-scaled by 10*log2(e): MFMA directly yields base-2 logits a'.
// sum 2^{a'} <= 16384 * 2^14.43 ~ 3.6e8 -> fits fp32, no max-subtract needed.
#define SCALE1 14.426950408889634f   // 10 * log2(e)

typedef __bf16 bf16_t;
typedef __bf16 bf16x8 __attribute__((ext_vector_type(8)));
typedef __bf16 bf16x4 __attribute__((ext_vector_type(4)));
typedef float  f32x4  __attribute__((ext_vector_type(4)));

static __device__ __forceinline__ float fast_exp2(float x) {
#if __has_builtin(__builtin_amdgcn_exp2f)
    return __builtin_amdgcn_exp2f(x);
#else
    return __expf(x * 0.6931471805599453f);
#endif
}

// ------- Kernel 1: L2-normalize both rows, cast to bf16, exact fp32 pos -----
__global__ __launch_bounds__(256) void normalize_kernel(
    const float* __restrict__ v1, const float* __restrict__ v2,
    bf16_t* __restrict__ v1n, bf16_t* __restrict__ v2n,
    float* __restrict__ pos, int n)
{
    const int row  = blockIdx.x * 4 + (threadIdx.x >> 6);
    const int lane = threadIdx.x & 63;
    if (row >= n) return;
    const float4 a = *reinterpret_cast<const float4*>(v1 + (size_t)row * D_DIM + lane * 4);
    const float4 b = *reinterpret_cast<const float4*>(v2 + (size_t)row * D_DIM + lane * 4);
    float ss1 = a.x * a.x + a.y * a.y + a.z * a.z + a.w * a.w;
    float ss2 = b.x * b.x + b.y * b.y + b.z * b.z + b.w * b.w;
    float dt  = a.x * b.x + a.y * b.y + a.z * b.z + a.w * b.w;
    #pragma unroll
    for (int off = 1; off < 64; off <<= 1) {
        ss1 += __shfl_xor(ss1, off);
        ss2 += __shfl_xor(ss2, off);
        dt  += __shfl_xor(dt,  off);
    }
    const float n1 = fmaxf(sqrtf(ss1), 1e-12f);
    const float n2 = fmaxf(sqrtf(ss2), 1e-12f);
    const float s1 = SCALE1 / n1;
    const float s2 = 1.0f   / n2;
    bf16x4 o1, o2;
    o1[0] = (bf16_t)(a.x * s1); o1[1] = (bf16_t)(a.y * s1);
    o1[2] = (bf16_t)(a.z * s1); o1[3] = (bf16_t)(a.w * s1);
    o2[0] = (bf16_t)(b.x * s2); o2[1] = (bf16_t)(b.y * s2);
    o2[2] = (bf16_t)(b.z * s2); o2[3] = (bf16_t)(b.w * s2);
    *reinterpret_cast<bf16x4*>(v1n + (size_t)row * D_DIM + lane * 4) = o1;
    *reinterpret_cast<bf16x4*>(v2n + (size_t)row * D_DIM + lane * 4) = o2;
    if (lane == 0) pos[row] = 10.0f * dt / (n1 * n2);
}

// ------- Kernel 2: base-2 logits + row sum of 2^logit ----------------------
// Swapped-operand MFMA: D = A(v2 tile) * B(v1 frag); D col (=lane&15) indexes
// the v1 row -> each lane's 4 acc values belong to ONE v1 row. G=4 row-groups
// per wave, bfrag PINNED in VGPRs via "+v" asm (compiler may not remat /
// reload from L2 -- round-9's hidden cost: VGPR=104 < 128 needed, refetched
// every iter). 32-row v2 tiles double-buffered via global_load_lds (linear
// dest, XOR-pre-swizzled source; ds_read applies same XOR).
__global__ __launch_bounds__(256, 2) void logits_kernel(
    const bf16_t* __restrict__ v1n, const bf16_t* __restrict__ v2n,
    float* __restrict__ partials)
{
    __shared__ bf16_t lds[2][TR * D_DIM];   // 2 x 16KB: [32 rows][256 bf16]

    const int tid  = threadIdx.x;
    const int w    = tid >> 6;
    const int lane = tid & 63;
    const int lo   = lane & 15;
    const int hi   = lane >> 4;
    const int xr   = lo & 7;                 // read-side XOR key
    const int r0w  = blockIdx.x * BM + w * (G * 16);

    // v1 fragments, register-resident for the whole sweep: [group][kk]
    bf16x8 bfrag[G][8];
    #pragma unroll
    for (int g = 0; g < G; ++g) {
        const bf16_t* v1p = v1n + (size_t)(r0w + g * 16 + lo) * D_DIM + hi * 8;
        #pragma unroll
        for (int kk = 0; kk < 8; ++kk)
            bfrag[g][kk] = *reinterpret_cast<const bf16x8*>(v1p + kk * 32);
    }
    // Pin fragments in VGPRs: "+v" turns each into an asm-defined value the
    // compiler cannot rematerialize from memory (forces true residency).
    #pragma unroll
    for (int g = 0; g < G; ++g)
        #pragma unroll
        for (int kk = 0; kk < 8; ++kk)
            asm volatile("" : "+v"(bfrag[g][kk]));

    const int cbase = blockIdx.y * CPB;
    float s[G];
    #pragma unroll
    for (int g = 0; g < G; ++g) s[g] = 0.f;

    // ---- stage tile 0 into buf 0 (source address pre-swizzled) ----
    #pragma unroll
    for (int j = 0; j < 4; ++j) {
        int r  = j * 8 + (tid >> 5);            // tile row 0..31
        int ch = (tid & 31) ^ (r & 7);          // swizzled 16B-chunk
        const bf16_t* gp = v2n + (size_t)(cbase + r) * D_DIM + ch * 8;
        __builtin_amdgcn_global_load_lds(
            (const __attribute__((address_space(1))) unsigned int*)gp,
            (__attribute__((address_space(3))) unsigned int*)(&lds[0][0] + j * 2048 + w * 512),
            16, 0, 0);
    }

    const int NT = CPB / TR;   // 64 tiles of 32 columns
    int cur = 0;
    for (int t = 0; t < NT; ++t) {
        asm volatile("s_waitcnt vmcnt(0)" ::: "memory");
        __builtin_amdgcn_s_barrier();
        asm volatile("" ::: "memory");

        // issue next tile's stage into the other buffer (in flight during MFMA)
        if (t + 1 < NT) {
            const int c0n = cbase + (t + 1) * TR;
            #pragma unroll
            for (int j = 0; j < 4; ++j) {
                int r  = j * 8 + (tid >> 5);
                int ch = (tid & 31) ^ (r & 7);
                const bf16_t* gp = v2n + (size_t)(c0n + r) * D_DIM + ch * 8;
                __builtin_amdgcn_global_load_lds(
                    (const __attribute__((address_space(1))) unsigned int*)gp,
                    (__attribute__((address_space(3))) unsigned int*)(&lds[cur ^ 1][0] + j * 2048 + w * 512),
                    16, 0, 0);
            }
        }

        const bf16_t* bufr = &lds[cur][0];
        #pragma unroll
        for (int sub = 0; sub < 2; ++sub) {      // two 16-row subtiles
            f32x4 acc[G];
            #pragma unroll
            for (int g = 0; g < G; ++g) acc[g] = (f32x4){0.f, 0.f, 0.f, 0.f};

            #pragma unroll
            for (int kk = 0; kk < 8; ++kk) {
                const int q = hi + 4 * kk;           // 16B-chunk index in row
                const bf16x8 a = *reinterpret_cast<const bf16x8*>(
                    bufr + (sub * 16 + lo) * 256 + ((q ^ xr) << 3));
                #pragma unroll
                for (int g = 0; g < G; ++g)
                    acc[g] = __builtin_amdgcn_mfma_f32_16x16x32_bf16(a, bfrag[g][kk], acc[g], 0, 0, 0);
            }

            // per logit: one v_exp_f32 + one add (no max-subtract needed)
            #pragma unroll
            for (int g = 0; g < G; ++g) {
                s[g] += (fast_exp2(acc[g][0]) + fast_exp2(acc[g][1]))
                      + (fast_exp2(acc[g][2]) + fast_exp2(acc[g][3]));
            }
        }

        asm volatile("" ::: "memory");
        __builtin_amdgcn_s_barrier();
        cur ^= 1;
    }

    // merge the 4 hi-lanes holding each row, write split partial
    #pragma unroll
    for (int g = 0; g < G; ++g) {
        float v = s[g];
        v += __shfl_xor(v, 16);
        v += __shfl_xor(v, 32);
        if (lane < 16)
            partials[(size_t)(r0w + g * 16 + lo) * SPLIT + blockIdx.y] = v;
    }
}

// ------- Kernel 3a: per-row loss + per-block partial sum -------------------
__global__ __launch_bounds__(256) void row_loss_kernel(
    const float* __restrict__ pos, const float* __restrict__ partials,
    float* __restrict__ bsum)
{
    const int row = blockIdx.x * 256 + threadIdx.x;
    float ssum = 0.f;
    #pragma unroll
    for (int p = 0; p < SPLIT; ++p)
        ssum += partials[(size_t)row * SPLIT + p];
    // ln(sum_j exp(logit_j)) == logf(sum_j 2^{a'_j})  (a' = logit*log2e)
    float loss = -pos[row] + logf(ssum);
    #pragma unroll
    for (int off = 1; off < 64; off <<= 1) loss += __shfl_xor(loss, off);
    __shared__ float ws4[4];
    if ((threadIdx.x & 63) == 0) ws4[threadIdx.x >> 6] = loss;
    __syncthreads();
    if (threadIdx.x == 0)
        bsum[blockIdx.x] = ws4[0] + ws4[1] + ws4[2] + ws4[3];
}

// ------- Kernel 3b: final mean ---------------------------------------------
__global__ void final_kernel(const float* __restrict__ bsum,
                             float* __restrict__ out, int nb, float invn)
{
    float v = (threadIdx.x < nb) ? bsum[threadIdx.x] : 0.f;
    #pragma unroll
    for (int off = 1; off < 64; off <<= 1) v += __shfl_xor(v, off);
    if (threadIdx.x == 0) out[0] = v * invn;
}

extern "C" void kernel_launch(void* const* d_in, const int* in_sizes, int n_in,
                              void* d_out, int out_size, void* d_ws, size_t ws_size,
                              hipStream_t stream)
{
    const float* view1 = (const float*)d_in[0];
    const float* view2 = (const float*)d_in[1];
    float* out = (float*)d_out;
    const int n = in_sizes[0] / D_DIM;   // 16384

    char* ws = (char*)d_ws;
    bf16_t* v1n = (bf16_t*)ws;                                    // 8 MB
    bf16_t* v2n = (bf16_t*)(ws + (size_t)n * D_DIM * 2);          // 8 MB
    char*   p2  = ws + (size_t)n * D_DIM * 4;
    float*  pos = (float*)p2;                                     // 64 KB
    float*  partials = (float*)(p2 + (size_t)n * 4);              // 512 KB
    float*  bsum = (float*)(p2 + (size_t)n * 4 + (size_t)n * SPLIT * 4); // 256 B

    // 1) normalize both views -> bf16 (+ exact fp32 pos)
    normalize_kernel<<<n / 4, 256, 0, stream>>>(view1, view2, v1n, v2n, pos, n);

    // 2) tiled base-2 logits + sumexp2 partials
    dim3 grid2(n / BM, SPLIT, 1);
    logits_kernel<<<grid2, 256, 0, stream>>>(v1n, v2n, partials);

    // 3) reduce
    row_loss_kernel<<<n / 256, 256, 0, stream>>>(pos, partials, bsum);
    final_kernel<<<1, 64, 0, stream>>>(bsum, out, n / 256, 1.0f / (float)n);
}